// Round 3
// baseline (125.511 us; speedup 1.0000x reference)
//
#include <hip/hip_runtime.h>

// Problem constants (match reference).
constexpr int Hh = 256;
constexpr int Ww = 256;
constexpr int Dd = 256;
constexpr int NB = 2048;

constexpr int CH = 16;   // scan elements per thread (chunk length)
constexpr int NC = 16;   // chunks per scan axis (256/16)
constexpr int D4 = 64;   // D in float4 units (one wave spans full D)

struct f4 { float x, y, z, w; };
__device__ __forceinline__ f4 operator+(f4 a, f4 b) {
    return {a.x + b.x, a.y + b.y, a.z + b.z, a.w + b.w};
}
__device__ __forceinline__ f4 operator-(f4 a, f4 b) {
    return {a.x - b.x, a.y - b.y, a.z - b.z, a.w - b.w};
}

// ---------------------------------------------------------------------------
// Pass 1: row-prefix along W. One block = one row h, all 256 channels.
// 1024 thr = 16 chunks x 64 lanes; lane owns float4 of d -> 1 KiB per wave
// load/store instruction. 16 scan elems/thread in registers; chunk totals
// scanned via LDS (wc is wave-uniform -> offset loop divergence-free).
// ---------------------------------------------------------------------------
__global__ void __launch_bounds__(1024) sat_row_prefix(const f4* __restrict__ feat,
                                                       f4* __restrict__ sat) {
    const int tid = threadIdx.x;
    const int dl  = tid & (D4 - 1);      // float4 lane over d
    const int wc  = tid >> 6;            // chunk index, wave-uniform
    const int h   = blockIdx.x;

    const size_t base = ((size_t)h * Ww + (size_t)wc * CH) * D4 + dl;
    const f4* src = feat + base;
    f4*       dst = sat + base;

    f4 v[CH];
#pragma unroll
    for (int j = 0; j < CH; ++j) v[j] = src[(size_t)j * D4];
#pragma unroll
    for (int j = 1; j < CH; ++j) v[j] = v[j] + v[j - 1];

    __shared__ f4 cs[NC][D4];
    cs[wc][dl] = v[CH - 1];
    __syncthreads();

    f4 off = {0.f, 0.f, 0.f, 0.f};
    for (int k = 0; k < wc; ++k) off = off + cs[k][dl];

#pragma unroll
    for (int j = 0; j < CH; ++j) dst[(size_t)j * D4] = v[j] + off;
}

// ---------------------------------------------------------------------------
// Pass 2: column-prefix along H, in place on sat. One block = one column w.
// Scan stride between elements is W*D4 float4s.
// ---------------------------------------------------------------------------
__global__ void __launch_bounds__(1024) sat_col_prefix(f4* __restrict__ sat) {
    const int tid = threadIdx.x;
    const int dl  = tid & (D4 - 1);
    const int hc  = tid >> 6;            // chunk index, wave-uniform
    const int w   = blockIdx.x;

    f4* p = sat + ((size_t)hc * CH * Ww + w) * D4 + dl;
    const size_t stride = (size_t)Ww * D4;

    f4 v[CH];
#pragma unroll
    for (int j = 0; j < CH; ++j) v[j] = p[(size_t)j * stride];
#pragma unroll
    for (int j = 1; j < CH; ++j) v[j] = v[j] + v[j - 1];

    __shared__ f4 cs[NC][D4];
    cs[hc][dl] = v[CH - 1];
    __syncthreads();

    f4 off = {0.f, 0.f, 0.f, 0.f};
    for (int k = 0; k < hc; ++k) off = off + cs[k][dl];

#pragma unroll
    for (int j = 0; j < CH; ++j) p[(size_t)j * stride] = v[j] + off;
}

// ---------------------------------------------------------------------------
// Pass 3: per-(box, 4-channel) 4-corner SAT lookup, float4 throughout.
// 64 lanes per box; bounds math replicates f32 JAX semantics exactly:
//   lo = max(0, floor(lo_f*size));  hi = rint(hi_f*size + 0.5)  (ties-even)
//   hi = min(size, max(lo+1, hi))
// ---------------------------------------------------------------------------
__global__ void __launch_bounds__(256) roi_pool_sat(const f4* __restrict__ sat,
                                                    const float* __restrict__ boxes,
                                                    f4* __restrict__ out) {
    int t  = blockIdx.x * blockDim.x + threadIdx.x;   // [0, NB*64)
    int n  = t >> 6;
    int dl = t & 63;

    float x1 = boxes[n * 4 + 0];
    float y1 = boxes[n * 4 + 1];
    float x2 = boxes[n * 4 + 2];
    float y2 = boxes[n * 4 + 3];

    int cl = max(0, (int)floorf(x1 * 256.0f));
    int ch = (int)rintf(x2 * 256.0f + 0.5f);
    ch = min(Ww, max(cl + 1, ch));

    int rl = max(0, (int)floorf(y1 * 256.0f));
    int rh = (int)rintf(y2 * 256.0f + 0.5f);
    rh = min(Hh, max(rl + 1, rh));

    f4 s = sat[(((size_t)(rh - 1) * Ww) + (ch - 1)) * D4 + dl];
    if (cl > 0) s = s - sat[(((size_t)(rh - 1) * Ww) + (cl - 1)) * D4 + dl];
    if (rl > 0) {
        s = s - sat[(((size_t)(rl - 1) * Ww) + (ch - 1)) * D4 + dl];
        if (cl > 0) s = s + sat[(((size_t)(rl - 1) * Ww) + (cl - 1)) * D4 + dl];
    }

    float count = (float)((rh - rl) * (ch - cl));
    f4 r = {s.x / count, s.y / count, s.z / count, s.w / count};
    out[(size_t)n * D4 + dl] = r;
}

// ---------------------------------------------------------------------------
// Fallback (only if ws too small for the 64 MiB SAT): direct summation.
// ---------------------------------------------------------------------------
__global__ void __launch_bounds__(256) roi_pool_naive(const float* __restrict__ feat,
                                                      const float* __restrict__ boxes,
                                                      float* __restrict__ out) {
    int n = blockIdx.x;
    int d = threadIdx.x;

    float x1 = boxes[n * 4 + 0];
    float y1 = boxes[n * 4 + 1];
    float x2 = boxes[n * 4 + 2];
    float y2 = boxes[n * 4 + 3];

    int cl = max(0, (int)floorf(x1 * 256.0f));
    int ch = (int)rintf(x2 * 256.0f + 0.5f);
    ch = min(Ww, max(cl + 1, ch));
    int rl = max(0, (int)floorf(y1 * 256.0f));
    int rh = (int)rintf(y2 * 256.0f + 0.5f);
    rh = min(Hh, max(rl + 1, rh));

    float s = 0.0f;
    for (int r = rl; r < rh; ++r) {
        const float* row = feat + ((size_t)r * Ww) * Dd + d;
        for (int c = cl; c < ch; ++c) s += row[(size_t)c * Dd];
    }
    float count = (float)((rh - rl) * (ch - cl));
    out[(size_t)n * Dd + d] = s / count;
}

extern "C" void kernel_launch(void* const* d_in, const int* in_sizes, int n_in,
                              void* d_out, int out_size, void* d_ws, size_t ws_size,
                              hipStream_t stream) {
    const float* feat  = (const float*)d_in[0];   // (256,256,256) f32
    const float* boxes = (const float*)d_in[1];   // (2048,4) f32

    const size_t sat_bytes = (size_t)Hh * Ww * Dd * sizeof(float);  // 64 MiB

    if (ws_size >= sat_bytes) {
        f4* sat = (f4*)d_ws;
        sat_row_prefix<<<Hh, 1024, 0, stream>>>((const f4*)feat, sat);
        sat_col_prefix<<<Ww, 1024, 0, stream>>>(sat);
        roi_pool_sat<<<(NB * D4) / 256, 256, 0, stream>>>(sat, boxes, (f4*)d_out);
    } else {
        roi_pool_naive<<<NB, 256, 0, stream>>>(feat, boxes, (float*)d_out);
    }
}